// Round 1
// baseline (11361.270 us; speedup 1.0000x reference)
//
#include <hip/hip_runtime.h>
#include <hip/hip_bf16.h>

// LSTM: T=512, B=64, H=512, L=2.  inputs: x[T,B,H] f32, Wh[L,H,4H], Wx[L,H,4H], bh[L,4H]
// out = concat(out[T,B,H], h_fin[L,B,H], c_fin[L,B,H]) f32.

#define TSEQ 512
#define BATCH 64
#define HID 512
#define H4 2048

typedef short bf16x8 __attribute__((ext_vector_type(8)));
typedef float f32x4 __attribute__((ext_vector_type(4)));

__device__ __forceinline__ ushort f32_to_bf16(float f) {
    unsigned u = __builtin_bit_cast(unsigned, f);
    u += 0x7FFFu + ((u >> 16) & 1u);   // round-to-nearest-even
    return (ushort)(u >> 16);
}

// ---- convert x f32 -> bf16 (vectorized) ----
__global__ __launch_bounds__(256) void convert_x(const float* __restrict__ x,
                                                 ushort* __restrict__ xq) {
    const int n4 = (TSEQ * BATCH * HID) / 4;
    int stride = gridDim.x * blockDim.x;
    for (int i = blockIdx.x * blockDim.x + threadIdx.x; i < n4; i += stride) {
        float4 v = ((const float4*)x)[i];
        ushort4 o;
        o.x = f32_to_bf16(v.x);
        o.y = f32_to_bf16(v.y);
        o.z = f32_to_bf16(v.z);
        o.w = f32_to_bf16(v.w);
        ((ushort4*)xq)[i] = o;
    }
}

// ---- transpose+convert weights: WT[m][n][k] = W[k][n], m: 0=Wx0 1=Wh0 2=Wx1 3=Wh1 ----
__global__ __launch_bounds__(256) void transpose_w(const float* __restrict__ Wh,
                                                   const float* __restrict__ Wx,
                                                   ushort* __restrict__ WT) {
    int bid = blockIdx.x;            // 4 * 8 * 32 = 1024 blocks
    int m  = bid >> 8;               // 0..3
    int kt = (bid >> 5) & 7;         // k tile (64)
    int nt = bid & 31;               // n tile (64)
    const float* src = ((m & 1) ? Wh : Wx) + (size_t)(m >> 1) * (HID * H4);

    __shared__ float tile[64][65];
    int c  = threadIdx.x & 63;
    int r0 = (threadIdx.x >> 6) * 16;
    for (int i = 0; i < 16; ++i) {
        int r = r0 + i;
        tile[r][c] = src[(size_t)(kt * 64 + r) * H4 + nt * 64 + c];
    }
    __syncthreads();
    int k  = threadIdx.x & 63;
    int n0 = (threadIdx.x >> 6) * 16;
    for (int i = 0; i < 16; ++i) {
        int n = n0 + i;
        WT[(size_t)m * (H4 * HID) + (size_t)(nt * 64 + n) * HID + kt * 64 + k] =
            f32_to_bf16(tile[k][n]);
    }
}

// ---- one pipeline stage: layer0 @ t=s (WGs 0..31), layer1 @ t=s-1 (WGs 32..63) ----
// WG owns hidden strip j0 = strip*16; wave g computes gate g's 64x16 tile.
__global__ __launch_bounds__(256) void lstm_stage(
    int s,
    const ushort* __restrict__ WT,   // [4][2048][512] bf16 (N-major, K contiguous)
    const ushort* __restrict__ xq,   // [512][64][512] bf16
    const float*  __restrict__ bh,   // [2][2048]
    ushort* __restrict__ h0q,        // [2][64][512] bf16 (ping-pong by t&1)
    ushort* __restrict__ h1q,        // [2][64][512]
    float*  __restrict__ c0,         // [64][512]
    float*  __restrict__ c1,         // [64][512]
    float*  __restrict__ out)        // d_out
{
    int w     = blockIdx.x;      // 0..63
    int layer = w >> 5;
    int strip = w & 31;
    int j0    = strip * 16;
    int t     = s - layer;
    if (t < 0 || t >= TSEQ) return;

    int wave = threadIdx.x >> 6;     // gate index 0..3 (i,f,g,o)
    int lane = threadIdx.x & 63;
    int lo   = lane & 15;
    int hi   = lane >> 4;

    const ushort *A1, *A2, *B1, *B2;
    if (layer == 0) {
        A1 = xq + (size_t)t * (BATCH * HID);
        A2 = h0q + (size_t)((t + 1) & 1) * (BATCH * HID);   // h0[t-1]
        B1 = WT + (size_t)0 * (H4 * HID);                   // Wx0^T
        B2 = WT + (size_t)1 * (H4 * HID);                   // Wh0^T
    } else {
        A1 = h0q + (size_t)(t & 1) * (BATCH * HID);         // h0[t]
        A2 = h1q + (size_t)((t + 1) & 1) * (BATCH * HID);   // h1[t-1]
        B1 = WT + (size_t)2 * (H4 * HID);                   // Wx1^T
        B2 = WT + (size_t)3 * (H4 * HID);                   // Wh1^T
    }

    // fragment base pointers (verified gemm_bt layout: k contiguous-8 per lane)
    const ushort* b1p = B1 + (size_t)(512 * wave + j0 + lo) * HID + hi * 8;
    const ushort* b2p = B2 + (size_t)(512 * wave + j0 + lo) * HID + hi * 8;
    const ushort* a1p = A1 + (size_t)lo * HID + hi * 8;
    const ushort* a2p = A2 + (size_t)lo * HID + hi * 8;

    f32x4 acc[4] = {(f32x4)(0.f), (f32x4)(0.f), (f32x4)(0.f), (f32x4)(0.f)};

#pragma unroll
    for (int kk = 0; kk < 16; ++kk) {
        bf16x8 b1 = *(const bf16x8*)(b1p + kk * 32);
        bf16x8 b2 = *(const bf16x8*)(b2p + kk * 32);
#pragma unroll
        for (int mt = 0; mt < 4; ++mt) {
            bf16x8 a1 = *(const bf16x8*)(a1p + mt * 16 * HID + kk * 32);
            acc[mt] = __builtin_amdgcn_mfma_f32_16x16x32_bf16(a1, b1, acc[mt], 0, 0, 0);
            bf16x8 a2 = *(const bf16x8*)(a2p + mt * 16 * HID + kk * 32);
            acc[mt] = __builtin_amdgcn_mfma_f32_16x16x32_bf16(a2, b2, acc[mt], 0, 0, 0);
        }
    }

    // gate tiles -> LDS (add bias here; bias depends on column only)
    __shared__ float lds_g[4][64][16];
    float bias = bh[layer * H4 + 512 * wave + j0 + lo];
#pragma unroll
    for (int mt = 0; mt < 4; ++mt) {
#pragma unroll
        for (int r = 0; r < 4; ++r) {
            int row = mt * 16 + hi * 4 + r;          // C/D layout: row=(lane>>4)*4+reg
            lds_g[wave][row][lo] = acc[mt][r] + bias; // col = lane&15
        }
    }
    __syncthreads();

    float* cc = (layer == 0) ? c0 : c1;
    ushort* hq = ((layer == 0) ? h0q : h1q) + (size_t)(t & 1) * (BATCH * HID);

#pragma unroll
    for (int q = 0; q < 4; ++q) {
        int cell = threadIdx.x + q * 256;    // 0..1023
        int b = cell >> 4;
        int c = cell & 15;
        float iv = lds_g[0][b][c];
        float fv = lds_g[1][b][c];
        float gv = lds_g[2][b][c];
        float ov = lds_g[3][b][c];
        float si = 1.f / (1.f + __expf(-iv));
        float sf = 1.f / (1.f + __expf(-fv));
        float so = 1.f / (1.f + __expf(-ov));
        float tg = tanhf(gv);
        size_t gidx = (size_t)b * HID + j0 + c;
        float cn = sf * cc[gidx] + si * tg;
        float hn = so * tanhf(cn);
        cc[gidx] = cn;
        hq[gidx] = f32_to_bf16(hn);
        if (layer == 1)
            out[(size_t)t * (BATCH * HID) + gidx] = hn;
        if (t == TSEQ - 1) {
            size_t base = (size_t)TSEQ * BATCH * HID;
            out[base + (size_t)layer * (BATCH * HID) + gidx] = hn;                       // h_fin
            out[base + (size_t)2 * (BATCH * HID) + (size_t)layer * (BATCH * HID) + gidx] = cn; // c_fin
        }
    }
}

extern "C" void kernel_launch(void* const* d_in, const int* in_sizes, int n_in,
                              void* d_out, int out_size, void* d_ws, size_t ws_size,
                              hipStream_t stream) {
    const float* x  = (const float*)d_in[0];
    const float* Wh = (const float*)d_in[1];
    const float* Wx = (const float*)d_in[2];
    const float* bh = (const float*)d_in[3];
    float* out = (float*)d_out;

    char* ws = (char*)d_ws;
    // layout: WT 8MB | xq 32MB | state 512KB  (total ~40.5MB)
    ushort* WT = (ushort*)ws;
    ushort* xq = (ushort*)(ws + ((size_t)8 << 20));
    char* state = ws + ((size_t)8 << 20) + ((size_t)32 << 20);
    ushort* h0q = (ushort*)state;                          // [2][64][512] bf16
    ushort* h1q = h0q + 2 * BATCH * HID;
    float* c0 = (float*)(h1q + 2 * BATCH * HID);           // [64][512] f32
    float* c1 = c0 + BATCH * HID;
    size_t state_bytes = (size_t)2 * 2 * BATCH * HID * sizeof(ushort)
                       + (size_t)2 * BATCH * HID * sizeof(float);

    hipMemsetAsync(state, 0, state_bytes, stream);
    convert_x<<<2048, 256, 0, stream>>>(x, xq);
    transpose_w<<<1024, 256, 0, stream>>>(Wh, Wx, WT);

    for (int s = 0; s <= TSEQ; ++s) {
        lstm_stage<<<64, 256, 0, stream>>>(s, WT, xq, bh, h0q, h1q, c0, c1, out);
    }
}